// Round 2
// baseline (241.724 us; speedup 1.0000x reference)
//
#include <hip/hip_runtime.h>

// TELIF: temporal-encoding LIF neuron scan.
// tx: [T, B, N] fp32, TE: [N, T] fp32, out ty: [T, B, N] fp32 (0/1 spikes).
// T=512, B=64, N=1024. One consumer thread per (b,n) sequence, sequential t.
//
// v3: FOUR independent producer/consumer pipelines per CU.
//   v2 (one 5-wave pipeline per CU, lockstep rounds) and v1 (register
//   prefetch) both measured ~73 us -> ~3.7 TB/s, vs 268 MB R+W roofline
//   ~43 us at 6.3 TB/s. Single-pipeline lockstep means every producer
//   hiccup stalls the whole CU. Now: 128-thread blocks = 1 consumer wave +
//   1 producer wave, 1024 blocks = 4 blocks/CU, each with a private 8-slot
//   LDS ring (32 KiB; 128 KiB/CU) and prefetch depth 7 (28 KB in flight per
//   block, 112 KB/CU >> 9 KB/CU bandwidth-delay product). Independent
//   2-wave barriers desync the pipelines and smooth HBM demand.
//   Producer packs 4 t-rows (64 floats = 256 B each) into one
//   global_load_lds dwordx4: per-lane global src (lane>>4 selects row,
//   lane&15 selects 16B column), wave-uniform LDS dest + lane*16.
//   Counted vmcnt (24 steady-state, ladder in the tail) -- never a full
//   drain inside the loop; raw s_barrier (no implicit vmcnt(0)).

#define T_STEPS 512
#define BATCH   64
#define NNEUR   1024
#define BN      (BATCH * NNEUR)
#define UCHUNK  16
#define NCHUNK  (T_STEPS / UCHUNK)   // 32
#define NSLOT   8                    // LDS ring depth (chunks)
#define AHEAD   7                    // max chunks issued ahead (NSLOT-1)
#define CONS_THREADS 64
#define BLOCK_THREADS 128            // 1 consumer wave + 1 producer wave

__global__ __launch_bounds__(BLOCK_THREADS) void telif_kernel(
    const float* __restrict__ tx, const float* __restrict__ TE,
    float* __restrict__ out)
{
    // Reference is validated against fp32 elementwise ops with a hard
    // (v > th) threshold: forbid FMA contraction so rounding matches exactly.
#pragma clang fp contract(off)

    // Ring: slot s holds one 16-step chunk of tx for this block's 64
    // sequences. 8 * 16 * 64 * 4 B = 32 KiB LDS -> 4 blocks/CU.
    __shared__ float buf[NSLOT][UCHUNK][CONS_THREADS];

    const int tid = threadIdx.x;
    const int blockBase = blockIdx.x * CONS_THREADS;   // first flat index

    if (tid >= CONS_THREADS) {
        // ---------------- producer wave (threads 64..127) ----------------
        const int lane = tid - CONS_THREADS;           // 0..63
        // One dwordx4 instr moves 4 t-rows of 256 B: lane l sources
        // row (l>>4), 16-B column (l&15); LDS dest is linear (uniform+l*16).
        const float* gbase = tx + blockBase + (lane & 15) * 4
                                + (size_t)(lane >> 4) * BN;

        auto issue_chunk = [&](int k) {
            const int slot = k & (NSLOT - 1);
#pragma unroll
            for (int p = 0; p < UCHUNK / 4; ++p) {     // 4 instrs per chunk
                const float* g = gbase + (size_t)(k * UCHUNK + p * 4) * BN;
                __builtin_amdgcn_global_load_lds(
                    (const __attribute__((address_space(1))) void*)g,
                    (__attribute__((address_space(3))) void*)&buf[slot][p * 4][0],
                    16, 0, 0);
            }
        };

        // Prologue: chunks 0..6 in flight (28 instrs); chunk 0 complete when
        // at most 24 (chunks 1..6) remain outstanding.
        for (int k = 0; k < AHEAD; ++k) issue_chunk(k);
        asm volatile("s_waitcnt vmcnt(24)" ::: "memory");
        __builtin_amdgcn_sched_barrier(0);
        __builtin_amdgcn_s_barrier();                  // chunk 0 ready

        for (int r = 0; r < NCHUNK; ++r) {
            // Slot (r+AHEAD)&7 held chunk r+AHEAD-8 < r: already consumed.
            if (r + AHEAD < NCHUNK) issue_chunk(r + AHEAD);
            // Guarantee chunk r+1 complete before opening round r+1.
            // Outstanding afterward: chunks r+2 .. min(r+AHEAD, 31),
            // i.e. 4*min(6, 30-r) instrs.
            if (r <= 24) {
                asm volatile("s_waitcnt vmcnt(24)" ::: "memory");
            } else if (r == 25) {
                asm volatile("s_waitcnt vmcnt(20)" ::: "memory");
            } else if (r == 26) {
                asm volatile("s_waitcnt vmcnt(16)" ::: "memory");
            } else if (r == 27) {
                asm volatile("s_waitcnt vmcnt(12)" ::: "memory");
            } else if (r == 28) {
                asm volatile("s_waitcnt vmcnt(8)" ::: "memory");
            } else if (r == 29) {
                asm volatile("s_waitcnt vmcnt(4)" ::: "memory");
            } else {
                asm volatile("s_waitcnt vmcnt(0)" ::: "memory");
            }
            __builtin_amdgcn_sched_barrier(0);
            __builtin_amdgcn_s_barrier();
        }
        return;
    }

    // ---------------- consumer wave (threads 0..63) ----------------
    const int flat = blockBase + tid;                  // b*N + n
    const int n = flat & (NNEUR - 1);
    const float* tep = TE + n * T_STEPS;               // contiguous along t
    float*       outp = out + flat;

    float v  = 0.0f;   // REST
    float y  = 0.0f;
    float th = 0.3f;   // THRESHOLD

    // TE double-buffer in registers (L1/L2-resident loads, one chunk ahead).
    float tc[UCHUNK], tn[UCHUNK];
#pragma unroll
    for (int u = 0; u < UCHUNK; u += 4) {
        float4 f = *reinterpret_cast<const float4*>(tep + u);
        tc[u] = f.x; tc[u + 1] = f.y; tc[u + 2] = f.z; tc[u + 3] = f.w;
    }
    __builtin_amdgcn_s_barrier();                      // chunk 0 ready

#pragma unroll 1
    for (int r = 0; r < NCHUNK; ++r) {
        const int t = r * UCHUNK;

        // Prefetch next chunk's TE into registers (issued before the round's
        // stores so the eventual vmcnt wait for them never drains stores).
        if (r + 1 < NCHUNK) {
#pragma unroll
            for (int u = 0; u < UCHUNK; u += 4) {
                float4 f = *reinterpret_cast<const float4*>(tep + t + UCHUNK + u);
                tn[u] = f.x; tn[u + 1] = f.y; tn[u + 2] = f.z; tn[u + 3] = f.w;
            }
        }

        // x from LDS: addr = tid*4 B, stride-1 across lanes -> 2 lanes/bank,
        // conflict-free. lgkmcnt waits only; stores never block the loop.
        const float* xs = &buf[r & (NSLOT - 1)][0][tid];
#pragma unroll
        for (int u = 0; u < UCHUNK; ++u) {
            float x = xs[(size_t)u * CONS_THREADS];
            // Exact op order of the reference:
            //   th = th + v*te - (th - THRESHOLD)*BETA
            //   v  = v*DECAY*(1-y) + x
            //   y  = (v > th)
            float a    = v * tc[u];
            float bsum = th + a;
            float c    = th - 0.3f;
            float d    = c * 0.02f;
            th = bsum - d;
            float e  = v * 0.2f;
            float f1 = 1.0f - y;
            float g  = e * f1;
            v = g + x;
            y = (v > th) ? 1.0f : 0.0f;
            __builtin_nontemporal_store(y, outp + (size_t)(t + u) * BN);
        }

#pragma unroll
        for (int u = 0; u < UCHUNK; ++u) tc[u] = tn[u];

        __builtin_amdgcn_s_barrier();                  // release slot r&7
    }
}

extern "C" void kernel_launch(void* const* d_in, const int* in_sizes, int n_in,
                              void* d_out, int out_size, void* d_ws, size_t ws_size,
                              hipStream_t stream) {
    const float* tx = (const float*)d_in[0];  // [T, B, N]
    const float* TE = (const float*)d_in[1];  // [N, T]
    float* out = (float*)d_out;               // [T, B, N]
    telif_kernel<<<BN / CONS_THREADS, BLOCK_THREADS, 0, stream>>>(tx, TE, out);
}

// Round 3
// 233.392 us; speedup vs baseline: 1.0357x; 1.0357x over previous
//
#include <hip/hip_runtime.h>

// TELIF: temporal-encoding LIF neuron scan.
// tx: [T, B, N] fp32, TE: [N, T] fp32, out ty: [T, B, N] fp32 (0/1 spikes).
// T=512, B=64, N=1024. One thread per (b,n) sequence; sequential over t.
//
// v4: back to the all-consumer register-prefetch structure (v1, best
// measured), with three changes driven by v3's counters:
//   1. tx loads are PLAIN (no nontemporal hint). FETCH_SIZE=66.6MB showed
//      L3 already retains ~half of tx across dispatches despite the 537MB
//      poison fills; tx (134MB) fits in the 256MB Infinity Cache. The v1
//      nt-load hint actively fought residency. Stores stay nontemporal so
//      `out` streams to HBM without polluting L3.
//   2. UCHUNK 16->32: 8KB in flight per wave, half the chunk-boundary
//      drains (16 instead of 32).
//   3. Chunked XCD swizzle: dispatch round-robins blocks across the 8 XCDs,
//      so remap bid -> (bid%8)*32 + bid/8. Each XCD's 32 blocks then cover
//      a CONTIGUOUS 32KB span of every t-row -> denser per-L2 miss stream.
// v3 lesson (kept out): producer/consumer LDS pipeline with 112KB/CU in
// flight was SLOWER (86us vs ~75) -> not latency-bound; don't re-add.

#define T_STEPS 512
#define BATCH   64
#define NNEUR   1024
#define BN      (BATCH * NNEUR)
#define UCHUNK  32
#define NXCD    8

__global__ __launch_bounds__(256) void telif_kernel(
    const float* __restrict__ tx, const float* __restrict__ TE,
    float* __restrict__ out)
{
    // Reference is validated against fp32 elementwise ops with a hard
    // (v > th) threshold: forbid FMA contraction so rounding matches exactly.
#pragma clang fp contract(off)

    // Chunked XCD swizzle: 256 blocks, XCD x owns logical blocks
    // [x*32, (x+1)*32) -> contiguous 32KB of each 256KB t-row per XCD/L2.
    const int bid = blockIdx.x;
    const int swz = (bid & (NXCD - 1)) * (256 / NXCD) + (bid >> 3);

    const int flat = swz * 256 + threadIdx.x;   // b*N + n
    const int n = flat & (NNEUR - 1);

    const float* txp = tx + flat;        // stride BN along t, coalesced across lanes
    const float* tep = TE + n * T_STEPS; // contiguous along t per thread
    float*       outp = out + flat;

    float v  = 0.0f;   // REST
    float y  = 0.0f;
    float th = 0.3f;   // THRESHOLD

    float xc[UCHUNK], tc[UCHUNK];  // current chunk
    float xn[UCHUNK], tn[UCHUNK];  // next chunk (prefetch)

    // Prefetch chunk 0. Plain loads: allocate tx in L2/L3 (stays resident).
#pragma unroll
    for (int u = 0; u < UCHUNK; ++u)
        xc[u] = txp[(size_t)u * BN];
#pragma unroll
    for (int u = 0; u < UCHUNK; u += 4) {
        float4 f = *reinterpret_cast<const float4*>(tep + u);
        tc[u] = f.x; tc[u + 1] = f.y; tc[u + 2] = f.z; tc[u + 3] = f.w;
    }

#pragma unroll 1
    for (int t = 0; t < T_STEPS; t += UCHUNK) {
        const int tb = t + UCHUNK;
        if (tb < T_STEPS) {
            // Issue next chunk's loads before computing current chunk:
            // ~32 tx loads + 8 float4 TE loads in flight per wave. Loads
            // precede this round's stores in program order, so the rotate's
            // vmcnt wait never has to drain the stores (in-order counter).
#pragma unroll
            for (int u = 0; u < UCHUNK; ++u)
                xn[u] = txp[(size_t)(tb + u) * BN];
#pragma unroll
            for (int u = 0; u < UCHUNK; u += 4) {
                float4 f = *reinterpret_cast<const float4*>(tep + tb + u);
                tn[u] = f.x; tn[u + 1] = f.y; tn[u + 2] = f.z; tn[u + 3] = f.w;
            }
        }

        // Compute current chunk. Exact op order of the reference:
        //   th = th + v*te - (th - THRESHOLD)*BETA
        //   v  = v*DECAY*(1-y) + x
        //   y  = (v > th)
#pragma unroll
        for (int u = 0; u < UCHUNK; ++u) {
            float a    = v * tc[u];
            float bsum = th + a;
            float c    = th - 0.3f;
            float d    = c * 0.02f;
            th = bsum - d;
            float e  = v * 0.2f;
            float f1 = 1.0f - y;
            float g  = e * f1;
            v = g + xc[u];
            y = (v > th) ? 1.0f : 0.0f;
            __builtin_nontemporal_store(y, outp + (size_t)(t + u) * BN);
        }

        // Rotate buffers (register moves; garbage on last iter is unused).
#pragma unroll
        for (int u = 0; u < UCHUNK; ++u) { xc[u] = xn[u]; tc[u] = tn[u]; }
    }
}

extern "C" void kernel_launch(void* const* d_in, const int* in_sizes, int n_in,
                              void* d_out, int out_size, void* d_ws, size_t ws_size,
                              hipStream_t stream) {
    const float* tx = (const float*)d_in[0];  // [T, B, N]
    const float* TE = (const float*)d_in[1];  // [N, T]
    float* out = (float*)d_out;               // [T, B, N]
    telif_kernel<<<BN / 256, 256, 0, stream>>>(tx, TE, out);
}